// Round 7
// baseline (212.658 us; speedup 1.0000x reference)
//
#include <hip/hip_runtime.h>

#define NJ 1024
#define DETECT 0.5f
#define RESCUE 0.4975f   // 0.5 minus u8 error bound (0.00196), with margin

__device__ __forceinline__ float sample_t(int s) {
    // jnp.linspace(0,1,64) fp32 semantics (endpoint exactly 1.0)
    return (s == 63) ? 1.0f : (float)s * (1.0f / 63.0f);
}

// Exact fp32 recompute for pair (a -> weight t, b -> weight 1-t), reference op order.
__device__ __forceinline__ void exact_pair(const float2 ja, const float2 jb,
                                           const float* __restrict__ heat,
                                           float& mean_o, float& min_o)
{
    float acc = 0.0f;
    float mn  = __builtin_inff();
    for (int s = 0; s < 64; ++s) {
        const float t  = sample_t(s);
        const float om = 1.0f - t;
        float ch = __fadd_rn(__fmul_rn(ja.x, t), __fmul_rn(jb.x, om));
        float cw = __fadd_rn(__fmul_rn(ja.y, t), __fmul_rn(jb.y, om));
        ch = fminf(fmaxf(ch, 0.0f), 1023.0f);
        cw = fminf(fmaxf(cw, 0.0f), 1023.0f);
        const float hf = floorf(ch), hc = ceilf(ch);
        const float wf = floorf(cw), wc = ceilf(cw);
        const int hfi = (int)hf, hci = (int)hc;
        const int wfi = (int)wf, wci = (int)wc;
        const float a00 = heat[(hfi << 10) + wfi];
        const float a01 = heat[(hfi << 10) + wci];
        const float a10 = heat[(hci << 10) + wfi];
        const float a11 = heat[(hci << 10) + wci];
        const float t1 = __fmul_rn(__fmul_rn(a00, __fsub_rn(hc, ch)), __fsub_rn(wc, cw));
        const float t2 = __fmul_rn(__fmul_rn(a01, __fsub_rn(hc, ch)), __fsub_rn(cw, wf));
        const float t3 = __fmul_rn(__fmul_rn(a10, __fsub_rn(ch, hf)), __fsub_rn(wc, cw));
        const float t4 = __fmul_rn(__fmul_rn(a11, __fsub_rn(ch, hf)), __fsub_rn(cw, wf));
        const float feat = __fadd_rn(__fadd_rn(__fadd_rn(t1, t2), t3), t4);
        acc += feat;
        mn = fminf(mn, feat);
    }
    mean_o = acc * (1.0f / 64.0f);
    min_o  = mn;
}

// Stage: packed[h][w] = 2x2 corner block as 4x u8 in one dword (4 MB, L2-resident).
// Lane 0 of each block additionally computes diagonal cell (r,r) exactly.
__global__ __launch_bounds__(256) void pack_kernel(
    const float* __restrict__ heat, uint4* __restrict__ packed4,
    const float* __restrict__ junc,
    float* __restrict__ line_out, float* __restrict__ mean_out)
{
    const int idx = blockIdx.x * 256 + threadIdx.x;   // 0 .. 256K-1
    const int h = idx >> 8;                           // row
    const int w4 = (idx & 255) << 2;                  // first of 4 cells
    const int hn = (h < 1023) ? h + 1 : 1023;
    const float* r0 = heat + (h  << 10);
    const float* r1 = heat + (hn << 10);
    const float4 a = *(const float4*)(r0 + w4);
    const float4 b = *(const float4*)(r1 + w4);
    const int wnext = (w4 + 4 <= 1023) ? w4 + 4 : 1023;
    const float a4 = r0[wnext];
    const float b4 = r1[wnext];

    const float av[5] = {a.x, a.y, a.z, a.w, a4};
    const float bv[5] = {b.x, b.y, b.z, b.w, b4};
    unsigned int out[4];
    #pragma unroll
    for (int u = 0; u < 4; ++u) {
        const unsigned int c0 = (unsigned int)__float2int_rn(av[u]     * 255.0f);
        const unsigned int c1 = (unsigned int)__float2int_rn(av[u + 1] * 255.0f);
        const unsigned int c2 = (unsigned int)__float2int_rn(bv[u]     * 255.0f);
        const unsigned int c3 = (unsigned int)__float2int_rn(bv[u + 1] * 255.0f);
        out[u] = c0 | (c1 << 8) | (c2 << 16) | (c3 << 24);
    }
    packed4[idx] = make_uint4(out[0], out[1], out[2], out[3]);

    // Diagonal pair (r,r): exact, line=0 (strict upper-tri mask excludes diagonal).
    if (threadIdx.x == 0) {
        const int r = blockIdx.x;          // 1024 blocks -> all diagonal cells
        const float2 jr = ((const float2*)junc)[r];
        float mean, mnv;
        exact_pair(jr, jr, heat, mean, mnv);
        const int p = (r << 10) + r;
        mean_out[p] = mean;
        line_out[p] = 0.0f;
    }
}

// One thread per pair-orientation, band c in [1,512]:
// q in [0, 1024*512) ; r = q>>9 ; c = (q&511)+1 ; j = (r+c) mod 1024.
// Exactly 2048 blocks of 256 -> 8 blocks/CU, zero straggler tail.
// d==512 pairs appear in both orientations, each writing its own cell.
__global__ __launch_bounds__(256) void sold2_thread_kernel(
    const float* __restrict__ junc,          // [N,2] (h,w)
    const float* __restrict__ heat,          // [H,W] fp32 (exact rescue path)
    const unsigned int* __restrict__ packed, // [H,W] u8x4 corner blocks
    float* __restrict__ line_out,            // [N,N] float 0/1
    float* __restrict__ mean_out)            // [N,N]
{
    const int q = blockIdx.x * 256 + threadIdx.x;   // 0 .. 524287
    const int r = q >> 9;
    const int c = (q & 511) + 1;
    const int j = (r + c) & 1023;

    const float2 jr  = ((const float2*)junc)[r];
    const float2 jjc = ((const float2*)junc)[j];

    float acc = 0.0f;           // in u8 counts (x255)
    float mn  = __builtin_inff();

    #pragma unroll
    for (int s0 = 0; s0 < 64; s0 += 16) {
        float chv[16], cwv[16];
        unsigned int cv[16];
        #pragma unroll
        for (int u = 0; u < 16; ++u) {
            const int s = s0 + u;
            const float t  = sample_t(s);
            const float om = 1.0f - t;
            // Reference op order: ji*t + jj*(1-t), contraction-proof.
            float ch = __fadd_rn(__fmul_rn(jr.x, t), __fmul_rn(jjc.x, om));
            float cw = __fadd_rn(__fmul_rn(jr.y, t), __fmul_rn(jjc.y, om));
            ch = fminf(fmaxf(ch, 0.0f), 1023.0f);
            cw = fminf(fmaxf(cw, 0.0f), 1023.0f);
            chv[u] = ch;
            cwv[u] = cw;
            const int hfi = (int)ch;   // trunc == floor for non-negative
            const int wfi = (int)cw;
            cv[u] = packed[(hfi << 10) + wfi];
        }
        #pragma unroll
        for (int u = 0; u < 16; ++u) {
            const float ch = chv[u], cw = cwv[u];
            const float hf = floorf(ch), hc = ceilf(ch);
            const float wf = floorf(cw), wc = ceilf(cw);
            const float wh0 = hc - ch, wh1 = ch - hf;
            const float ww0 = wc - cw, ww1 = cw - wf;
            const unsigned int cc = cv[u];
            const float a00 = (float)(cc & 0xffu);
            const float a01 = (float)((cc >> 8) & 0xffu);
            const float a10 = (float)((cc >> 16) & 0xffu);
            const float a11 = (float)(cc >> 24);
            const float feat = a00 * (wh0 * ww0) + a01 * (wh0 * ww1)
                             + a10 * (wh1 * ww0) + a11 * (wh1 * ww1);
            acc += feat;
            mn = fminf(mn, feat);
        }
    }

    float mean = acc * (1.0f / (255.0f * 64.0f));
    const float mns = mn * (1.0f / 255.0f);

    // Conservative candidate test: exact detection implies u8 min/mean > RESCUE.
    bool det = false;
    if ((mns > RESCUE) && (mean > RESCUE)) {
        float mn2;
        exact_pair(jr, jjc, heat, mean, mn2);
        det = (mean > DETECT) && (mn2 > DETECT);
    }

    const int p1 = (r << 10) + j;
    mean_out[p1] = mean;                 // coalesced (consecutive j per row)
    line_out[p1] = det ? 1.0f : 0.0f;
}

// Fill complement band (d = (j-i) mod 1024 in [513,1023]) from the mirror cell:
// out[i][j] = out[j][i]. LDS-tiled 64x64 transpose; blocks fully outside the
// band exit before any loads.
__global__ __launch_bounds__(256) void mirror_kernel(
    float* __restrict__ line_out, float* __restrict__ mean_out)
{
    __shared__ float lm[64][65];
    __shared__ float mm[64][65];
    const int bi = blockIdx.x >> 4;      // dst tile row block
    const int bj = blockIdx.x & 15;      // dst tile col block

    // d over the tile = (64*(bj-bi) + delta) mod 1024, delta in [-63,63].
    // Entirely inside [0,512] (i.e. no band cells) iff D in [63,449].
    const int D = ((bj - bi) << 6) & 1023;
    if (D >= 63 && D <= 449) return;

    const int tx = threadIdx.x & 63;
    const int g  = threadIdx.x >> 6;     // 0..3

    #pragma unroll
    for (int k = 0; k < 16; ++k) {
        const int b = (g << 4) + k;
        const int src = ((bj << 6) + b) * 1024 + (bi << 6) + tx;
        lm[b][tx] = line_out[src];
        mm[b][tx] = mean_out[src];
    }
    __syncthreads();

    #pragma unroll
    for (int k = 0; k < 16; ++k) {
        const int a = (g << 4) + k;
        const int i = (bi << 6) + a;
        const int j = (bj << 6) + tx;
        const int d = (j - i) & 1023;
        if (d >= 513) {
            const int dst = i * 1024 + j;
            line_out[dst] = lm[tx][a];
            mean_out[dst] = mm[tx][a];
        }
    }
}

extern "C" void kernel_launch(void* const* d_in, const int* in_sizes, int n_in,
                              void* d_out, int out_size, void* d_ws, size_t ws_size,
                              hipStream_t stream) {
    const float* junc = (const float*)d_in[0];   // [1024,2] float32
    const float* heat = (const float*)d_in[1];   // [1024,1024] float32
    float* line_out = (float*)d_out;
    float* mean_out = line_out + NJ * NJ;

    unsigned int* packed = (unsigned int*)d_ws;  // 4 MB scratch
    pack_kernel<<<1024, 256, 0, stream>>>(heat, (uint4*)packed, junc,
                                          line_out, mean_out);

    sold2_thread_kernel<<<2048, 256, 0, stream>>>(junc, heat, packed,
                                                  line_out, mean_out);

    mirror_kernel<<<256, 256, 0, stream>>>(line_out, mean_out);
}